// Round 7
// baseline (88.845 us; speedup 1.0000x reference)
//
#include <hip/hip_runtime.h>
#include <hip/hip_bf16.h>

#define NMOD 64
#define INPD 256
#define OUTD 256
#define BATCH 2048
#define TT 64

typedef __attribute__((ext_vector_type(8))) short short8;
typedef __attribute__((ext_vector_type(4))) float floatx4;

// RNE f32 pair -> packed bf16x2 via v_cvt_pk_bf16_f32 (1 VALU op; same RNE
// rounding as the old bit-trick, verified round 6: absmax unchanged).
__device__ __forceinline__ unsigned int pack2(float a, float b) {
    union { __hip_bfloat162 h; unsigned int u; } cv;
    cv.h = __float22bfloat162_rn(make_float2(a, b));
    return cv.u;
}

// Repack W [e][n][k] f32 -> fragment-major bf16 (round-0 verified layout):
//   Wpack elem index = (((e*8 + ks)*16 + frag)*64 + lane)*8 + j
//   frag = w*4 + ni  (wave w owns cols w*64..w*64+63; ni = 16-col group)
//   source n = (frag>>3)*128 + (frag&7)*16 + (lane&15)
//   source k = ks*32 + (lane>>4)*8 + j
// GEMM B-loads then become lane-contiguous 1024B bursts.
__global__ __launch_bounds__(256) void conv_w_kernel(const float* __restrict__ W,
                                                     uint4* __restrict__ Wp) {
    int gid  = blockIdx.x * 256 + threadIdx.x;   // 0 .. 524287 (one 8-elem frag slice)
    int lane = gid & 63;
    int frag = (gid >> 6) & 15;
    int ks   = (gid >> 10) & 7;
    int e    = gid >> 13;

    int n = (frag >> 3) * 128 + (frag & 7) * 16 + (lane & 15);
    int k = ks * 32 + (lane >> 4) * 8;

    const float* p = W + ((size_t)e * OUTD + n) * INPD + k;
    float4 v0 = *reinterpret_cast<const float4*>(p);
    float4 v1 = *reinterpret_cast<const float4*>(p + 4);
    Wp[gid] = make_uint4(pack2(v0.x, v0.y), pack2(v0.z, v0.w),
                         pack2(v1.x, v1.y), pack2(v1.z, v1.w));
}

// Round-0 structure EXACTLY (best measured: 74.8 us bench): one block per
// sample, 4 waves, wave w owns cols [w*64,w*64+64) (disjoint W -> W read once
// per sample), x[b] staged via tid-coalesced float4 loads into XOR-swizzled
// LDS, fragment-major Wpack B-loads, acc[4][4]. Block turnover across the
// 2048-block grid provides the stage/compute/store phase stagger (rounds 5/6
// proved explicit in-block pipelining is not better).
// Changes vs round 0 (register-level only, both verified in rounds 3-6):
//  - MFMA operands SWAPPED (W as A-op, x as B-op): D[o][t] gives each lane 4
//    consecutive output cols -> 16 float4 stores instead of 64 scalar stores.
//  - pack2 via v_cvt_pk_bf16_f32: staging VALU ~256 -> ~32 ops/lane.
template <bool PRECONV>
__global__ __launch_bounds__(256) void moe_gemm_kernel(
    const float* __restrict__ x, const int* __restrict__ idx,
    const void* __restrict__ Wsrc, const float* __restrict__ bias,
    float* __restrict__ y) {

    __shared__ unsigned short lx[TT * INPD];   // 32 KiB, XOR-swizzled layout

    const int b    = blockIdx.x;
    const int tid  = threadIdx.x;
    const int lane = tid & 63;
    const int w    = tid >> 6;
    const int e    = idx[b];
    const int l15  = lane & 15;
    const int kq   = lane >> 4;

    // ---- stage x[b] (64x256 f32) into LDS as bf16, XOR-swizzled ----
    const float4* xin = reinterpret_cast<const float4*>(x + (size_t)b * TT * INPD);
    char* lxc = reinterpret_cast<char*>(lx);
#pragma unroll
    for (int r = 0; r < 16; ++r) {
        int fid  = r * 256 + tid;        // float4 index within the 64x256 tile
        float4 v = xin[fid];
        int t    = fid >> 6;             // row (token)
        int k    = (fid & 63) * 4;       // col, multiple of 4
        int byte = t * 512 + ((k * 2) ^ ((t & 7) << 4));
        __builtin_assume((byte & 7) == 0);
        *reinterpret_cast<uint2*>(lxc + byte) = make_uint2(pack2(v.x, v.y), pack2(v.z, v.w));
    }
    __syncthreads();

    floatx4 acc[4][4] = {};

#pragma unroll
    for (int ks = 0; ks < 8; ++ks) {
        // A fragments: lane holds x[t = mi*16 + l15][k = ks*32 + kq*8 .. +7]
        short8 af[4];
#pragma unroll
        for (int mi = 0; mi < 4; ++mi) {
            int t    = mi * 16 + l15;
            int byte = t * 512 + ((ks * 64 + kq * 16) ^ ((t & 7) << 4));
            __builtin_assume((byte & 15) == 0);
            af[mi] = *reinterpret_cast<const short8*>(lxc + byte);
        }
        // B fragments: lane holds W[n = w*64 + ni*16 + l15][k = ks*32 + kq*8 .. +7]
        short8 bf[4];
        if (PRECONV) {
            // fragment-major: elem = ((e*8+ks)*16 + w*4 + ni)*512 + lane*8
            const unsigned short* wp = reinterpret_cast<const unsigned short*>(Wsrc)
                + (((size_t)e * 8 + ks) << 13) + (w << 11) + (lane << 3);
#pragma unroll
            for (int ni = 0; ni < 4; ++ni)
                bf[ni] = *reinterpret_cast<const short8*>(wp + (ni << 9));
        } else {
            const float* Wf = reinterpret_cast<const float*>(Wsrc) + (size_t)e * OUTD * INPD;
#pragma unroll
            for (int ni = 0; ni < 4; ++ni) {
                int n = w * 64 + ni * 16 + l15;
                int k = ks * 32 + kq * 8;
                const float* p = Wf + (size_t)n * INPD + k;
                float4 v0 = *reinterpret_cast<const float4*>(p);
                float4 v1 = *reinterpret_cast<const float4*>(p + 4);
                union { short8 s; uint4 u; } cv;
                cv.u = make_uint4(pack2(v0.x, v0.y), pack2(v0.z, v0.w),
                                  pack2(v1.x, v1.y), pack2(v1.z, v1.w));
                bf[ni] = cv.s;
            }
        }
        // Swapped operands: D[m=o][n=t] = sum_k W[o][k] * x[t][k]
#pragma unroll
        for (int mi = 0; mi < 4; ++mi)
#pragma unroll
            for (int ni = 0; ni < 4; ++ni)
                acc[mi][ni] = __builtin_amdgcn_mfma_f32_16x16x32_bf16(
                    bf[ni], af[mi], acc[mi][ni], 0, 0, 0);
    }

    // Epilogue (swapped-D layout, verified rounds 3-6): col = lane&15 -> token
    // within mi-group, row = kq*4+r -> output col within ni-group => each lane
    // holds 4 consecutive output cols for one token: float4 store, float4 bias.
    const floatx4* bp = reinterpret_cast<const floatx4*>(bias + e * OUTD + w * 64) + kq;
    floatx4 bv[4];
#pragma unroll
    for (int ni = 0; ni < 4; ++ni)
        bv[ni] = bp[ni * 4];

    float* yb = y + ((size_t)b * TT + l15) * OUTD + w * 64 + kq * 4;
#pragma unroll
    for (int mi = 0; mi < 4; ++mi) {
        float* yrow = yb + mi * (16 * OUTD);
#pragma unroll
        for (int ni = 0; ni < 4; ++ni)
            *reinterpret_cast<floatx4*>(yrow + ni * 16) = acc[mi][ni] + bv[ni];
    }
}

extern "C" void kernel_launch(void* const* d_in, const int* in_sizes, int n_in,
                              void* d_out, int out_size, void* d_ws, size_t ws_size,
                              hipStream_t stream) {
    const float* x    = (const float*)d_in[0];   // [2048, 64, 256] f32
    const int*   idx  = (const int*)d_in[1];     // [2048] i32
    const float* W    = (const float*)d_in[2];   // [64, 256, 256] f32
    const float* bias = (const float*)d_in[3];   // [64, 256] f32
    float*       y    = (float*)d_out;           // [2048, 64, 256] f32

    const size_t w_elems      = (size_t)NMOD * OUTD * INPD;          // 4,194,304
    const size_t w_bf16_bytes = w_elems * sizeof(unsigned short);    // 8 MiB

    if (ws_size >= w_bf16_bytes) {
        conv_w_kernel<<<(unsigned)(w_elems / 8 / 256), 256, 0, stream>>>(
            W, reinterpret_cast<uint4*>(d_ws));
        moe_gemm_kernel<true><<<BATCH, 256, 0, stream>>>(x, idx, d_ws, bias, y);
    } else {
        moe_gemm_kernel<false><<<BATCH, 256, 0, stream>>>(x, idx, (const void*)W, bias, y);
    }
}

// Round 8
// 77.601 us; speedup vs baseline: 1.1449x; 1.1449x over previous
//
#include <hip/hip_runtime.h>
#include <hip/hip_bf16.h>

#define NMOD 64
#define INPD 256
#define OUTD 256
#define BATCH 2048
#define TT 64

typedef __attribute__((ext_vector_type(8))) short short8;
typedef __attribute__((ext_vector_type(4))) float floatx4;

// RNE f32 pair -> packed bf16x2 via v_cvt_pk_bf16_f32 (1 VALU op; same RNE
// rounding as the original bit-trick, verified rounds 6/7: absmax unchanged).
__device__ __forceinline__ unsigned int pack2(float a, float b) {
    union { __hip_bfloat162 h; unsigned int u; } cv;
    cv.h = __float22bfloat162_rn(make_float2(a, b));
    return cv.u;
}

// Repack W [e][n][k] f32 -> fragment-major bf16 (round-0 verified layout):
//   Wpack elem index = (((e*8 + ks)*16 + frag)*64 + lane)*8 + j
//   frag = w*4 + ni  (wave w owns cols w*64..w*64+63; ni = 16-col group)
//   source n = (frag>>3)*128 + (frag&7)*16 + (lane&15)
//   source k = ks*32 + (lane>>4)*8 + j
__global__ __launch_bounds__(256) void conv_w_kernel(const float* __restrict__ W,
                                                     uint4* __restrict__ Wp) {
    int gid  = blockIdx.x * 256 + threadIdx.x;
    int lane = gid & 63;
    int frag = (gid >> 6) & 15;
    int ks   = (gid >> 10) & 7;
    int e    = gid >> 13;

    int n = (frag >> 3) * 128 + (frag & 7) * 16 + (lane & 15);
    int k = ks * 32 + (lane >> 4) * 8;

    const float* p = W + ((size_t)e * OUTD + n) * INPD + k;
    float4 v0 = *reinterpret_cast<const float4*>(p);
    float4 v1 = *reinterpret_cast<const float4*>(p + 4);
    Wp[gid] = make_uint4(pack2(v0.x, v0.y), pack2(v0.z, v0.w),
                         pack2(v1.x, v1.y), pack2(v1.z, v1.w));
}

// Counting sort of samples by expert id: order[] lists sample ids grouped by
// expert. Co-scheduled gemm blocks then share one expert's 128 KB Wpack slice
// -> B-fragment loads hit L2 instead of L3 (latency play; HBM bytes unchanged).
// One block, 1024 threads, 2 samples each. Order within an expert arbitrary.
__global__ __launch_bounds__(1024) void sort_kernel(const int* __restrict__ idx,
                                                    int* __restrict__ order) {
    __shared__ int hist[NMOD];
    const int tid = threadIdx.x;
    if (tid < NMOD) hist[tid] = 0;
    __syncthreads();

    const int e0 = idx[tid];
    const int e1 = idx[tid + 1024];
    atomicAdd(&hist[e0], 1);
    atomicAdd(&hist[e1], 1);
    __syncthreads();

    if (tid < 64) {                      // exactly wave 0 on gfx950
        int v   = hist[tid];
        int sum = v;
#pragma unroll
        for (int off = 1; off < 64; off <<= 1) {
            int n = __shfl_up(sum, off, 64);
            if (tid >= off) sum += n;
        }
        hist[tid] = sum - v;             // exclusive prefix -> cursor
    }
    __syncthreads();

    int p0 = atomicAdd(&hist[e0], 1);
    order[p0] = tid;
    int p1 = atomicAdd(&hist[e1], 1);
    order[p1] = tid + 1024;
}

// Round-0 structure (best measured): one block per sample, 4 waves, wave w
// owns cols [w*64,w*64+64) (disjoint W -> W read once per sample), x[b] staged
// via tid-coalesced float4 loads into XOR-swizzled LDS, fragment-major Wpack
// B-loads, acc[4][4]. Changes vs round 0:
//  - MFMA operands SWAPPED (W as A-op): lane owns 4 consecutive output cols
//    -> 16 float4 stores instead of 64 scalar stores (r7-verified).
//  - bias folded into accumulator INIT (acc[mi][ni] = bv[ni], mi-independent)
//    so no bias regs live across the K-loop: fixes r7's 136-reg overflow.
//  - launch_bounds(256,4) pins unified VGPR+AGPR <= 128 -> 4 waves/SIMD.
//  - blocks process samples in expert-sorted order (order[]) for L2 B-locality.
template <bool PRECONV>
__global__ __launch_bounds__(256, 4) void moe_gemm_kernel(
    const float* __restrict__ x, const int* __restrict__ idx,
    const void* __restrict__ Wsrc, const float* __restrict__ bias,
    float* __restrict__ y, const int* __restrict__ order) {

    __shared__ unsigned short lx[TT * INPD];   // 32 KiB, XOR-swizzled layout

    const int b    = PRECONV ? order[blockIdx.x] : blockIdx.x;
    const int tid  = threadIdx.x;
    const int lane = tid & 63;
    const int w    = tid >> 6;
    const int e    = idx[b];
    const int l15  = lane & 15;
    const int kq   = lane >> 4;

    // ---- bias -> accumulator init (bv dead after this; no epilogue adds) ----
    // Swapped-D layout: acc[mi][ni][r] -> y[mi*16+l15][w*64 + ni*16 + kq*4 + r],
    // so the bias element bv[ni][r] = bias[w*64 + ni*16 + kq*4 + r] is the same
    // for all mi.
    const floatx4* bp = reinterpret_cast<const floatx4*>(bias + e * OUTD + w * 64) + kq;
    floatx4 acc[4][4];
#pragma unroll
    for (int ni = 0; ni < 4; ++ni) {
        floatx4 bv = bp[ni * 4];
#pragma unroll
        for (int mi = 0; mi < 4; ++mi)
            acc[mi][ni] = bv;
    }

    // ---- stage x[b] (64x256 f32) into LDS as bf16, XOR-swizzled ----
    const float4* xin = reinterpret_cast<const float4*>(x + (size_t)b * TT * INPD);
    char* lxc = reinterpret_cast<char*>(lx);
#pragma unroll
    for (int r = 0; r < 16; ++r) {
        int fid  = r * 256 + tid;        // float4 index within the 64x256 tile
        float4 v = xin[fid];
        int t    = fid >> 6;             // row (token)
        int k    = (fid & 63) * 4;       // col, multiple of 4
        int byte = t * 512 + ((k * 2) ^ ((t & 7) << 4));
        __builtin_assume((byte & 7) == 0);
        *reinterpret_cast<uint2*>(lxc + byte) = make_uint2(pack2(v.x, v.y), pack2(v.z, v.w));
    }
    __syncthreads();

#pragma unroll
    for (int ks = 0; ks < 8; ++ks) {
        // A fragments: lane holds x[t = mi*16 + l15][k = ks*32 + kq*8 .. +7]
        short8 af[4];
#pragma unroll
        for (int mi = 0; mi < 4; ++mi) {
            int t    = mi * 16 + l15;
            int byte = t * 512 + ((ks * 64 + kq * 16) ^ ((t & 7) << 4));
            __builtin_assume((byte & 15) == 0);
            af[mi] = *reinterpret_cast<const short8*>(lxc + byte);
        }
        // B fragments: lane holds W[n = w*64 + ni*16 + l15][k = ks*32 + kq*8 .. +7]
        short8 bf[4];
        if (PRECONV) {
            // fragment-major: elem = ((e*8+ks)*16 + w*4 + ni)*512 + lane*8
            const unsigned short* wp = reinterpret_cast<const unsigned short*>(Wsrc)
                + (((size_t)e * 8 + ks) << 13) + (w << 11) + (lane << 3);
#pragma unroll
            for (int ni = 0; ni < 4; ++ni)
                bf[ni] = *reinterpret_cast<const short8*>(wp + (ni << 9));
        } else {
            const float* Wf = reinterpret_cast<const float*>(Wsrc) + (size_t)e * OUTD * INPD;
#pragma unroll
            for (int ni = 0; ni < 4; ++ni) {
                int n = w * 64 + ni * 16 + l15;
                int k = ks * 32 + kq * 8;
                const float* p = Wf + (size_t)n * INPD + k;
                float4 v0 = *reinterpret_cast<const float4*>(p);
                float4 v1 = *reinterpret_cast<const float4*>(p + 4);
                union { short8 s; uint4 u; } cv;
                cv.u = make_uint4(pack2(v0.x, v0.y), pack2(v0.z, v0.w),
                                  pack2(v1.x, v1.y), pack2(v1.z, v1.w));
                bf[ni] = cv.s;
            }
        }
        // Swapped operands: D[m=o][n=t] = sum_k W[o][k] * x[t][k]
#pragma unroll
        for (int mi = 0; mi < 4; ++mi)
#pragma unroll
            for (int ni = 0; ni < 4; ++ni)
                acc[mi][ni] = __builtin_amdgcn_mfma_f32_16x16x32_bf16(
                    bf[ni], af[mi], acc[mi][ni], 0, 0, 0);
    }

    // ---- epilogue: pure float4 stores (bias already in acc) ----
    float* yb = y + ((size_t)b * TT + l15) * OUTD + w * 64 + kq * 4;
#pragma unroll
    for (int mi = 0; mi < 4; ++mi) {
        float* yrow = yb + mi * (16 * OUTD);
#pragma unroll
        for (int ni = 0; ni < 4; ++ni)
            *reinterpret_cast<floatx4*>(yrow + ni * 16) = acc[mi][ni];
    }
}

extern "C" void kernel_launch(void* const* d_in, const int* in_sizes, int n_in,
                              void* d_out, int out_size, void* d_ws, size_t ws_size,
                              hipStream_t stream) {
    const float* x    = (const float*)d_in[0];   // [2048, 64, 256] f32
    const int*   idx  = (const int*)d_in[1];     // [2048] i32
    const float* W    = (const float*)d_in[2];   // [64, 256, 256] f32
    const float* bias = (const float*)d_in[3];   // [64, 256] f32
    float*       y    = (float*)d_out;           // [2048, 64, 256] f32

    const size_t w_elems      = (size_t)NMOD * OUTD * INPD;          // 4,194,304
    const size_t w_bf16_bytes = w_elems * sizeof(unsigned short);    // 8 MiB
    const size_t order_bytes  = (size_t)BATCH * sizeof(int);         // 8 KiB

    if (ws_size >= w_bf16_bytes + order_bytes) {
        int* order = reinterpret_cast<int*>((char*)d_ws + w_bf16_bytes);
        conv_w_kernel<<<(unsigned)(w_elems / 8 / 256), 256, 0, stream>>>(
            W, reinterpret_cast<uint4*>(d_ws));
        sort_kernel<<<1, 1024, 0, stream>>>(idx, order);
        moe_gemm_kernel<true><<<BATCH, 256, 0, stream>>>(x, idx, d_ws, bias, y, order);
    } else {
        moe_gemm_kernel<false><<<BATCH, 256, 0, stream>>>(x, idx, (const void*)W, bias, y, nullptr);
    }
}